// Round 10
// baseline (183.776 us; speedup 1.0000x reference)
//
#include <hip/hip_runtime.h>

#define HH 256
#define WW 256
#define HWPX 65536
#define BB 8
#define KK 21
#define CC 32
#define NTB 2048                // affinity blocks (4 stacked tiles per wave)
#define E_LOG2E 1.4426950408889634f
#define PEN -30000.0f           // exp2(PEN + bounded dot) flushes to exactly +0

typedef _Float16 half2v __attribute__((ext_vector_type(2)));
typedef _Float16 half8  __attribute__((ext_vector_type(8)));
typedef float    f32x4v __attribute__((ext_vector_type(4)));
union F4H { float4 f4; half2v h[4]; half8 h8; };

// ---------------- kernel 1: T + |q|^2 + planar f16 pack, 1 px/thread (known-good) ----------------
// Also zeroes out[0] (stream-ordered before reduce_fin's atomicAdds).
__global__ __launch_bounds__(256) void prep(const float* __restrict__ cls,
                                            const float* __restrict__ feat,
                                            float4* __restrict__ fpk,
                                            float2* __restrict__ TN,
                                            float* __restrict__ out) {
    const int tid = blockIdx.x * 256 + threadIdx.x;   // 0..524287 (b*HWPX+p)
    if (tid == 0) out[0] = 0.f;
    const int b = tid >> 16;
    const int p = tid & (HWPX - 1);

    const float* cbase = cls + (size_t)b * KK * HWPX + p;
    float T = 0.f;
#pragma unroll
    for (int k = 0; k < KK; ++k) T += cbase[(size_t)k * HWPX];

    const float* src = feat + (size_t)b * CC * HWPX + p;
    float nq = 0.f;
#pragma unroll
    for (int j = 0; j < 4; ++j) {
        F4H u;
#pragma unroll
        for (int k = 0; k < 4; ++k) {
            float a  = src[(size_t)(j * 8 + 2 * k) * HWPX];
            float b2 = src[(size_t)(j * 8 + 2 * k + 1) * HWPX];
            u.h[k] = __builtin_bit_cast(half2v, __builtin_amdgcn_cvt_pkrtz(a, b2));
            nq = __builtin_amdgcn_fdot2(u.h[k], u.h[k], nq, false);
        }
        fpk[(size_t)j * (BB * HWPX) + tid] = u.f4;
    }
    TN[tid] = make_float2(T, nq);
}

// ---------------- kernel 2 (hot): MFMA affinity, FOUR stacked 2x8 tiles per wave ----------------
// Wave owns rows y0..y0+7 x cols x0..x0+7 as tiles Tk at rows (y0+2k, y0+2k+1), k=0..3.
// 16 windows ny in [y0-4, y0+11] serve all 4 tiles (tile k active for i in [2k, 2k+9]) ->
// 16 B/TN loads for 40 MFMA activations (4 loads/tile vs r9's 6, r6's 10). Register diet:
// one base cst array per tile (L16 validity) + shared ok9/ok4 masks per r-parity, applied by
// a single select only at activations needing a tighter dx^2 limit (D=9 or 16). All tile /
// window constants compile-time via fully-unrolled loops (rule #20).
__global__ __launch_bounds__(256) void affinity_mfma(const float4* __restrict__ fpk,
                                                     const float2* __restrict__ TN,
                                                     const float* __restrict__ cls,
                                                     float* __restrict__ partial) {
    __shared__ float smN[4][21], smD[4][21];
    const int L    = blockIdx.x;        // 0..2047 ; L%8 = batch (XCD swizzle)
    const int b    = L & 7;
    const int t    = L >> 3;            // 0..255
    const int wid  = threadIdx.x >> 6;
    const int lane = threadIdx.x & 63;
    const int g    = lane >> 4;         // k-chunk = feature plane
    const int c    = lane & 15;         // fragment col
    const int idx  = t * 4 + wid;       // tile-quad id 0..1023
    const int y0   = (idx >> 5) * 8;    // rows y0..y0+7
    const int x0   = (idx & 31) * 8;    // cols x0..x0+7

    const size_t bofs = (size_t)b * HWPX;
    const float4* fb  = fpk + bofs;
    const float2* tnb = TN + bofs;

    // A fragments: tile k px (y0+2k+(c&1), x0+(c>>1)), channels 8g..8g+7
    F4H afr[4];
#pragma unroll
    for (int k = 0; k < 4; ++k)
        afr[k].f4 = fb[(size_t)g * (BB * HWPX) + ((y0 + 2 * k + (c & 1)) << 8) + x0 + (c >> 1)];

    // own-px indices for my 4 C-rows of tile 0: m = 4g+r -> (ry=r&1, rx=2g+(r>>1));
    // tile k adds 2k image rows (+512k)
    int pxr[4];
#pragma unroll
    for (int r = 0; r < 4; ++r)
        pxr[r] = ((y0 + (r & 1)) << 8) + x0 + 2 * g + (r >> 1);

    // B window x = x0-4+c ; loop-invariant byte offsets + validity
    const int xbu  = x0 - 4 + c;
    const bool inb = (unsigned)xbu < WW;
    const int xbc  = min(max(xbu, 0), WW - 1);
    const int voffF = (g * (BB * HWPX) + xbc) * 16;
    const int voffT = xbc * 8;

    // base cst per (tile, reg): -E/16*dx2 - E*np, PEN if x-OOB or dx2>16 (L16 validity).
    // shared per-parity masks for tighter limits (dx depends on r only through h=r>>1).
    float cstB[4][4];
    bool ok9[2], ok4[2];
#pragma unroll
    for (int h = 0; h < 2; ++h) {
        const int dx = c - 4 - 2 * g - h;
        ok9[h] = dx * dx <= 9;
        ok4[h] = dx * dx <= 4;
    }
#pragma unroll
    for (int k = 0; k < 4; ++k)
#pragma unroll
        for (int r = 0; r < 4; ++r) {
            const int dx = c - 4 - 2 * g - (r >> 1);
            const int s2 = dx * dx;
            const float npE = tnb[pxr[r] + 512 * k].y * E_LOG2E;
            cstB[k][r] = (inb && s2 <= 16) ? fmaf((float)s2, -E_LOG2E / 16.f, -npE) : PEN;
        }

    const f32x4v czero = {0.f, 0.f, 0.f, 0.f};
    float pd[4][4], pv[4][4];
#pragma unroll
    for (int k = 0; k < 4; ++k)
#pragma unroll
        for (int r = 0; r < 4; ++r) { pd[k][r] = 0.f; pv[k][r] = 0.f; }

    const char* fpkB = (const char*)fpk + bofs * 16;   // plane-0, batch b (bytes)
    const char* tnB  = (const char*)TN + bofs * 8;

    // select with compile-time limit: 0 -> base, 1 -> need dx2<=9, 2 -> need dx2<=4
#define SEL(BASE, LIM, H) ((LIM) == 0 ? (BASE) : ((LIM) == 1 ? (ok9[H] ? (BASE) : PEN) \
                                                             : (ok4[H] ? (BASE) : PEN)))

#pragma unroll
    for (int i = 0; i < 16; ++i) {
        const int ny = y0 - 4 + i;                    // wave-uniform
        if ((unsigned)ny >= HH) continue;
        F4H bfr; bfr.f4 = *(const float4*)(fpkB + ((size_t)ny << 12) + voffF);
        const float2 tq = *(const float2*)(tnB  + ((size_t)ny << 11) + voffT);
#pragma unroll
        for (int k = 0; k < 4; ++k) {
            if (i < 2 * k || i > 2 * k + 9) continue;  // tile inactive at this window
            const int DE   = (i - 4 - 2 * k) * (i - 4 - 2 * k);   // even regs dy^2
            const int DO   = (i - 5 - 2 * k) * (i - 5 - 2 * k);   // odd regs dy^2
            const int mode = (i == 2 * k) ? 1 : ((i == 2 * k + 9) ? 2 : 0);
            const int limE = DE <= 4 ? 0 : (DE == 9 ? 1 : 2);
            const int limO = DO <= 4 ? 0 : (DO == 9 ? 1 : 2);
            f32x4v cz = __builtin_amdgcn_mfma_f32_16x16x32_f16(afr[k].h8, bfr.h8, czero, 0, 0, 0);
            if (mode != 2) {
                const float te = fmaf(tq.y, -E_LOG2E, (float)DE * (-E_LOG2E / 16.f));
                const float e0 = fmaf(cz[0], 2.f * E_LOG2E, SEL(cstB[k][0], limE, 0) + te);
                const float w0 = __builtin_exp2f(e0);
                pd[k][0] += w0;  pv[k][0] = fmaf(w0, tq.x, pv[k][0]);
                const float e2 = fmaf(cz[2], 2.f * E_LOG2E, SEL(cstB[k][2], limE, 1) + te);
                const float w2 = __builtin_exp2f(e2);
                pd[k][2] += w2;  pv[k][2] = fmaf(w2, tq.x, pv[k][2]);
            }
            if (mode != 1) {
                const float to = fmaf(tq.y, -E_LOG2E, (float)DO * (-E_LOG2E / 16.f));
                const float e1 = fmaf(cz[1], 2.f * E_LOG2E, SEL(cstB[k][1], limO, 0) + to);
                const float w1 = __builtin_exp2f(e1);
                pd[k][1] += w1;  pv[k][1] = fmaf(w1, tq.x, pv[k][1]);
                const float e3 = fmaf(cz[3], 2.f * E_LOG2E, SEL(cstB[k][3], limO, 1) + to);
                const float w3 = __builtin_exp2f(e3);
                pd[k][3] += w3;  pv[k][3] = fmaf(w3, tq.x, pv[k][3]);
            }
        }
    }
#undef SEL

    // col-sum over the 16 B cols (butterfly within 16-lane group), all tiles
#pragma unroll
    for (int m = 1; m <= 8; m <<= 1)
#pragma unroll
        for (int k = 0; k < 4; ++k)
#pragma unroll
            for (int r = 0; r < 4; ++r) {
                pd[k][r] += __shfl_xor(pd[k][r], m, 64);
                pv[k][r] += __shfl_xor(pv[k][r], m, 64);
            }

    // fused cls reduce: lane c handles j=c (and j=c+16 for c<5) over its 16 own px
    float n0 = 0.f, d0 = 0.f, n1 = 0.f, d1 = 0.f;
    const float* clsb = cls + (size_t)b * KK * HWPX;
#pragma unroll
    for (int r = 0; r < 4; ++r)
#pragma unroll
        for (int k = 0; k < 4; ++k) {
            const float s0 = clsb[(size_t)c * HWPX + pxr[r] + 512 * k];
            n0 = fmaf(s0, pv[k][r], n0);
            d0 = fmaf(s0, pd[k][r], d0);
            if (c < 5) {
                const float s1 = clsb[(size_t)(c + 16) * HWPX + pxr[r] + 512 * k];
                n1 = fmaf(s1, pv[k][r], n1);
                d1 = fmaf(s1, pd[k][r], d1);
            }
        }
#pragma unroll
    for (int m = 16; m <= 32; m <<= 1) {
        n0 += __shfl_xor(n0, m, 64);
        d0 += __shfl_xor(d0, m, 64);
        n1 += __shfl_xor(n1, m, 64);
        d1 += __shfl_xor(d1, m, 64);
    }
    if (lane < 16) {
        smN[wid][lane] = n0;
        smD[wid][lane] = d0;
        if (lane < 5) { smN[wid][16 + lane] = n1; smD[wid][16 + lane] = d1; }
    }
    __syncthreads();
    if (threadIdx.x < 2 * KK) {                      // 42 partial slots per block, no atomics
        const int jq = threadIdx.x;
        const float v = (jq < KK)
            ? (smN[0][jq] + smN[1][jq] + smN[2][jq] + smN[3][jq])
            : (smD[0][jq - KK] + smD[1][jq - KK] + smD[2][jq - KK] + smD[3][jq - KK]);
        partial[(size_t)jq * NTB + (size_t)b * 256 + t] = v;
    }
}

// ---------------- kernel 3: per-(b,j) partial sums -> atomicAdd(out, N/D) ----------------
__global__ __launch_bounds__(256) void reduce_fin(const float* __restrict__ partial,
                                                  float* __restrict__ out) {
    __shared__ float smn[4], smd[4];
    const int j = blockIdx.x;    // 0..20
    const int b = blockIdx.y;    // 0..7
    float n = partial[(size_t)j        * NTB + (size_t)b * 256 + threadIdx.x];
    float d = partial[(size_t)(j + KK) * NTB + (size_t)b * 256 + threadIdx.x];
#pragma unroll
    for (int off = 32; off > 0; off >>= 1) {
        n += __shfl_down(n, off);
        d += __shfl_down(d, off);
    }
    if ((threadIdx.x & 63) == 0) { smn[threadIdx.x >> 6] = n; smd[threadIdx.x >> 6] = d; }
    __syncthreads();
    if (threadIdx.x == 0) {
        const float N = (smn[0] + smn[1]) + (smn[2] + smn[3]);
        const float D = (smd[0] + smd[1]) + (smd[2] + smd[3]);
        atomicAdd(out, N / D);
    }
}

extern "C" void kernel_launch(void* const* d_in, const int* in_sizes, int n_in,
                              void* d_out, int out_size, void* d_ws, size_t ws_size,
                              hipStream_t stream) {
    const float* cls  = (const float*)d_in[0];  // [B,K,H,W]
    const float* feat = (const float*)d_in[1];  // [B,C,H,W]
    float* out = (float*)d_out;

    const size_t BHW = (size_t)BB * HWPX;
    // fpk (33.5 MB) | TN (4.2 MB) | partial (0.35 MB)   (~38 MB)
    float4* fpk     = (float4*)d_ws;
    float2* TN      = (float2*)((char*)d_ws + BHW * 64);
    float*  partial = (float*)((char*)TN + BHW * 8);

    prep<<<dim3((BB * HWPX) / 256), dim3(256), 0, stream>>>(cls, feat, fpk, TN, out);
    affinity_mfma<<<dim3(NTB), dim3(256), 0, stream>>>(fpk, TN, cls, partial);
    reduce_fin<<<dim3(KK, BB), dim3(256), 0, stream>>>(partial, out);
}

// Round 11
// 173.902 us; speedup vs baseline: 1.0568x; 1.0568x over previous
//
#include <hip/hip_runtime.h>

#define HH 256
#define WW 256
#define HWPX 65536
#define BB 8
#define KK 21
#define CC 32
#define NTB 4096                // affinity blocks (2 stacked tiles per wave)
#define E_LOG2E 1.4426950408889634f
#define PEN -30000.0f           // exp2(PEN + bounded dot) flushes to exactly +0

typedef _Float16 half2v __attribute__((ext_vector_type(2)));
typedef _Float16 half8  __attribute__((ext_vector_type(8)));
typedef float    f32x4v __attribute__((ext_vector_type(4)));
union F4H { float4 f4; half2v h[4]; half8 h8; };

// ---------------- kernel 1: T + |q|^2 + planar f16 pack, 1 px/thread (known-good) ----------------
// Also zeroes out[0] (stream-ordered before reduce_fin's atomicAdds).
__global__ __launch_bounds__(256) void prep(const float* __restrict__ cls,
                                            const float* __restrict__ feat,
                                            float4* __restrict__ fpk,
                                            float2* __restrict__ TN,
                                            float* __restrict__ out) {
    const int tid = blockIdx.x * 256 + threadIdx.x;   // 0..524287 (b*HWPX+p)
    if (tid == 0) out[0] = 0.f;
    const int b = tid >> 16;
    const int p = tid & (HWPX - 1);

    const float* cbase = cls + (size_t)b * KK * HWPX + p;
    float T = 0.f;
#pragma unroll
    for (int k = 0; k < KK; ++k) T += cbase[(size_t)k * HWPX];

    const float* src = feat + (size_t)b * CC * HWPX + p;
    float nq = 0.f;
#pragma unroll
    for (int j = 0; j < 4; ++j) {
        F4H u;
#pragma unroll
        for (int k = 0; k < 4; ++k) {
            float a  = src[(size_t)(j * 8 + 2 * k) * HWPX];
            float b2 = src[(size_t)(j * 8 + 2 * k + 1) * HWPX];
            u.h[k] = __builtin_bit_cast(half2v, __builtin_amdgcn_cvt_pkrtz(a, b2));
            nq = __builtin_amdgcn_fdot2(u.h[k], u.h[k], nq, false);
        }
        fpk[(size_t)j * (BB * HWPX) + tid] = u.f4;
    }
    TN[tid] = make_float2(T, nq);
}

// ---------------- kernel 2 (hot): MFMA affinity, TWO stacked 2x8 tiles per wave ----------------
// ROUND-9 VERBATIM (best verified: affinity 46.8 us, total 176.0). r10's 4-tile + runtime-SEL
// variant regressed (57.6 us): selects added per-activation VALU; registers were never binding
// (r8: compiler used 28 of an 84 budget). Baked per-tile cst arrays are the right structure.
__global__ __launch_bounds__(256, 6) void affinity_mfma(const float4* __restrict__ fpk,
                                                        const float2* __restrict__ TN,
                                                        const float* __restrict__ cls,
                                                        float* __restrict__ partial) {
    __shared__ float smN[4][21], smD[4][21];
    const int L    = blockIdx.x;        // 0..4095 ; L%8 = batch (XCD swizzle)
    const int b    = L & 7;
    const int t    = L >> 3;            // 0..511
    const int wid  = threadIdx.x >> 6;
    const int lane = threadIdx.x & 63;
    const int g    = lane >> 4;         // k-chunk = feature plane
    const int c    = lane & 15;         // fragment col
    const int idx  = t * 4 + wid;       // tile-pair id 0..2047
    const int y0   = (idx >> 5) * 4;    // rows y0..y0+3
    const int x0   = (idx & 31) * 8;    // cols x0..x0+7

    const size_t bofs = (size_t)b * HWPX;
    const float4* fb  = fpk + bofs;
    const float2* tnb = TN + bofs;

    // A fragments: tile T0 px (y0+(c&1), x0+(c>>1)); T1 same +2 rows
    F4H afr0, afr1;
    afr0.f4 = fb[(size_t)g * (BB * HWPX) + ((y0 + (c & 1)) << 8) + x0 + (c >> 1)];
    afr1.f4 = fb[(size_t)g * (BB * HWPX) + ((y0 + 2 + (c & 1)) << 8) + x0 + (c >> 1)];

    // own-px indices for my 4 C-rows per tile: m = 4g+r -> (ry=r&1, rx=2g+(r>>1))
    int pxr0[4];
    float npE0[4], npE1[4];
#pragma unroll
    for (int r = 0; r < 4; ++r) {
        pxr0[r] = ((y0 + (r & 1)) << 8) + x0 + 2 * g + (r >> 1);
        npE0[r] = tnb[pxr0[r]].y * E_LOG2E;
        npE1[r] = tnb[pxr0[r] + 512].y * E_LOG2E;   // +2 image rows
    }

    // B window x = x0-4+c ; per-lane loop-invariant byte offsets + validity
    const int xbu  = x0 - 4 + c;
    const bool inb = (unsigned)xbu < WW;
    const int xbc  = min(max(xbu, 0), WW - 1);
    const int voffF = (g * (BB * HWPX) + xbc) * 16;
    const int voffT = xbc * 8;

    // 3 static cst arrays per tile keyed by dx^2 limit {16,9,4}; invalid -> PEN
    float c16_0[4], c9_0[4], c4_0[4], c16_1[4], c9_1[4], c4_1[4];
#pragma unroll
    for (int r = 0; r < 4; ++r) {
        const int dx = c - 4 - 2 * g - (r >> 1);
        const int s2 = dx * dx;
        const float bp0 = fmaf((float)s2, -E_LOG2E / 16.f, -npE0[r]);
        const float bp1 = fmaf((float)s2, -E_LOG2E / 16.f, -npE1[r]);
        c16_0[r] = (inb && s2 <= 16) ? bp0 : PEN;
        c9_0[r]  = (inb && s2 <= 9)  ? bp0 : PEN;
        c4_0[r]  = (inb && s2 <= 4)  ? bp0 : PEN;
        c16_1[r] = (inb && s2 <= 16) ? bp1 : PEN;
        c9_1[r]  = (inb && s2 <= 9)  ? bp1 : PEN;
        c4_1[r]  = (inb && s2 <= 4)  ? bp1 : PEN;
    }

    const f32x4v czero = {0.f, 0.f, 0.f, 0.f};
    float pd0[4] = {0.f, 0.f, 0.f, 0.f}, pv0[4] = {0.f, 0.f, 0.f, 0.f};
    float pd1[4] = {0.f, 0.f, 0.f, 0.f}, pv1[4] = {0.f, 0.f, 0.f, 0.f};

    const char* fpkB = (const char*)fpk + bofs * 16;   // plane-0, batch b (bytes)
    const char* tnB  = (const char*)TN + bofs * 8;

    // per-tile window body (r8-verified arithmetic). mode: 0=all regs, 1=even only, 2=odd only
    auto tbody = [&](const F4H& bfr, const float2& tq, const F4H& afr,
                     const float (&ce)[4], const float (&co)[4],
                     float (&pd)[4], float (&pv)[4],
                     float cdyE, float cdyO, int mode) {
        f32x4v cz = __builtin_amdgcn_mfma_f32_16x16x32_f16(afr.h8, bfr.h8, czero, 0, 0, 0);
        if (mode != 2) {
            const float te = fmaf(tq.y, -E_LOG2E, cdyE);
            const float e0 = fmaf(cz[0], 2.f * E_LOG2E, ce[0] + te);
            const float w0 = __builtin_exp2f(e0);
            pd[0] += w0;  pv[0] = fmaf(w0, tq.x, pv[0]);
            const float e2 = fmaf(cz[2], 2.f * E_LOG2E, ce[2] + te);
            const float w2 = __builtin_exp2f(e2);
            pd[2] += w2;  pv[2] = fmaf(w2, tq.x, pv[2]);
        }
        if (mode != 1) {
            const float to = fmaf(tq.y, -E_LOG2E, cdyO);
            const float e1 = fmaf(cz[1], 2.f * E_LOG2E, co[1] + to);
            const float w1 = __builtin_exp2f(e1);
            pd[1] += w1;  pv[1] = fmaf(w1, tq.x, pv[1]);
            const float e3 = fmaf(cz[3], 2.f * E_LOG2E, co[3] + to);
            const float w3 = __builtin_exp2f(e3);
            pd[3] += w3;  pv[3] = fmaf(w3, tq.x, pv[3]);
        }
    };

#define CDY(D) ((float)(D) * (-E_LOG2E / 16.f))
    // Window i (ny = y0-4+i). Tile T0: DE=(i-4)^2, DO=(i-5)^2; T1: shift i by -2.
    // lim map: D<=4 -> c16, D=9 -> c9, D=16 -> c4. T0 active i=0..9, T1 active i=2..11.
#define WIN(I, T0ACT, CE0, CO0, DE0, DO0, M0, T1ACT, CE1, CO1, DE1, DO1, M1)              \
    {                                                                                     \
        const int ny = y0 - 4 + (I);                                                      \
        if ((unsigned)ny < HH) {                                                          \
            F4H bfr; float2 tq;                                                           \
            bfr.f4 = *(const float4*)(fpkB + ((size_t)ny << 12) + voffF);                 \
            tq     = *(const float2*)(tnB  + ((size_t)ny << 11) + voffT);                 \
            if (T0ACT) tbody(bfr, tq, afr0, CE0, CO0, pd0, pv0, CDY(DE0), CDY(DO0), M0);  \
            if (T1ACT) tbody(bfr, tq, afr1, CE1, CO1, pd1, pv1, CDY(DE1), CDY(DO1), M1);  \
        }                                                                                 \
    }

    WIN(0,  1, c4_0,  c4_0,  16, 16, 1,   0, c4_1,  c4_1,  16, 16, 0)
    WIN(1,  1, c9_0,  c4_0,   9, 16, 0,   0, c4_1,  c4_1,  16, 16, 0)
    WIN(2,  1, c16_0, c9_0,   4,  9, 0,   1, c4_1,  c4_1,  16, 16, 1)
    WIN(3,  1, c16_0, c16_0,  1,  4, 0,   1, c9_1,  c4_1,   9, 16, 0)
    WIN(4,  1, c16_0, c16_0,  0,  1, 0,   1, c16_1, c9_1,   4,  9, 0)
    WIN(5,  1, c16_0, c16_0,  1,  0, 0,   1, c16_1, c16_1,  1,  4, 0)
    WIN(6,  1, c16_0, c16_0,  4,  1, 0,   1, c16_1, c16_1,  0,  1, 0)
    WIN(7,  1, c9_0,  c16_0,  9,  4, 0,   1, c16_1, c16_1,  1,  0, 0)
    WIN(8,  1, c4_0,  c9_0,  16,  9, 0,   1, c16_1, c16_1,  4,  1, 0)
    WIN(9,  1, c4_0,  c4_0,  16, 16, 2,   1, c9_1,  c16_1,  9,  4, 0)
    WIN(10, 0, c4_0,  c4_0,  16, 16, 0,   1, c4_1,  c9_1,  16,  9, 0)
    WIN(11, 0, c4_0,  c4_0,  16, 16, 0,   1, c4_1,  c4_1,  16, 16, 2)
#undef WIN
#undef CDY

    // col-sum over the 16 B cols (butterfly within 16-lane group), both tiles
#pragma unroll
    for (int m = 1; m <= 8; m <<= 1) {
#pragma unroll
        for (int r = 0; r < 4; ++r) {
            pd0[r] += __shfl_xor(pd0[r], m, 64);
            pv0[r] += __shfl_xor(pv0[r], m, 64);
            pd1[r] += __shfl_xor(pd1[r], m, 64);
            pv1[r] += __shfl_xor(pv1[r], m, 64);
        }
    }

    // fused cls reduce: lane c handles j=c (and j=c+16 for c<5) over its 8 own px (both tiles)
    float n0 = 0.f, d0 = 0.f, n1 = 0.f, d1 = 0.f;
    const float* clsb = cls + (size_t)b * KK * HWPX;
#pragma unroll
    for (int r = 0; r < 4; ++r) {
        const float s0a = clsb[(size_t)c * HWPX + pxr0[r]];
        const float s0b = clsb[(size_t)c * HWPX + pxr0[r] + 512];
        n0 = fmaf(s0a, pv0[r], n0);  n0 = fmaf(s0b, pv1[r], n0);
        d0 = fmaf(s0a, pd0[r], d0);  d0 = fmaf(s0b, pd1[r], d0);
        if (c < 5) {
            const float s1a = clsb[(size_t)(c + 16) * HWPX + pxr0[r]];
            const float s1b = clsb[(size_t)(c + 16) * HWPX + pxr0[r] + 512];
            n1 = fmaf(s1a, pv0[r], n1);  n1 = fmaf(s1b, pv1[r], n1);
            d1 = fmaf(s1a, pd0[r], d1);  d1 = fmaf(s1b, pd1[r], d1);
        }
    }
#pragma unroll
    for (int m = 16; m <= 32; m <<= 1) {
        n0 += __shfl_xor(n0, m, 64);
        d0 += __shfl_xor(d0, m, 64);
        n1 += __shfl_xor(n1, m, 64);
        d1 += __shfl_xor(d1, m, 64);
    }
    if (lane < 16) {
        smN[wid][lane] = n0;
        smD[wid][lane] = d0;
        if (lane < 5) { smN[wid][16 + lane] = n1; smD[wid][16 + lane] = d1; }
    }
    __syncthreads();
    if (threadIdx.x < 2 * KK) {                      // 42 partial slots per block, no atomics
        const int jq = threadIdx.x;
        const float v = (jq < KK)
            ? (smN[0][jq] + smN[1][jq] + smN[2][jq] + smN[3][jq])
            : (smD[0][jq - KK] + smD[1][jq - KK] + smD[2][jq - KK] + smD[3][jq - KK]);
        partial[(size_t)jq * NTB + (size_t)b * 512 + t] = v;
    }
}

// ---------------- kernel 3: per-(b,j) partial sums -> atomicAdd(out, N/D) ----------------
__global__ __launch_bounds__(256) void reduce_fin(const float* __restrict__ partial,
                                                  float* __restrict__ out) {
    __shared__ float smn[4], smd[4];
    const int j = blockIdx.x;    // 0..20
    const int b = blockIdx.y;    // 0..7
    const float2 n2 = ((const float2*)(partial + (size_t)j        * NTB + (size_t)b * 512))[threadIdx.x];
    const float2 d2 = ((const float2*)(partial + (size_t)(j + KK) * NTB + (size_t)b * 512))[threadIdx.x];
    float n = n2.x + n2.y;
    float d = d2.x + d2.y;
#pragma unroll
    for (int off = 32; off > 0; off >>= 1) {
        n += __shfl_down(n, off);
        d += __shfl_down(d, off);
    }
    if ((threadIdx.x & 63) == 0) { smn[threadIdx.x >> 6] = n; smd[threadIdx.x >> 6] = d; }
    __syncthreads();
    if (threadIdx.x == 0) {
        const float N = (smn[0] + smn[1]) + (smn[2] + smn[3]);
        const float D = (smd[0] + smd[1]) + (smd[2] + smd[3]);
        atomicAdd(out, N / D);
    }
}

extern "C" void kernel_launch(void* const* d_in, const int* in_sizes, int n_in,
                              void* d_out, int out_size, void* d_ws, size_t ws_size,
                              hipStream_t stream) {
    const float* cls  = (const float*)d_in[0];  // [B,K,H,W]
    const float* feat = (const float*)d_in[1];  // [B,C,H,W]
    float* out = (float*)d_out;

    const size_t BHW = (size_t)BB * HWPX;
    // fpk (33.5 MB) | TN (4.2 MB) | partial (0.7 MB)   (~38.4 MB)
    float4* fpk     = (float4*)d_ws;
    float2* TN      = (float2*)((char*)d_ws + BHW * 64);
    float*  partial = (float*)((char*)TN + BHW * 8);

    prep<<<dim3((BB * HWPX) / 256), dim3(256), 0, stream>>>(cls, feat, fpk, TN, out);
    affinity_mfma<<<dim3(NTB), dim3(256), 0, stream>>>(fpk, TN, cls, partial);
    reduce_fin<<<dim3(KK, BB), dim3(256), 0, stream>>>(partial, out);
}